// Round 2
// baseline (50.064 us; speedup 1.0000x reference)
//
#include <hip/hip_runtime.h>
#include <hip/hip_bf16.h>

typedef float f32x4 __attribute__((ext_vector_type(4)));
typedef __bf16 bf16x8 __attribute__((ext_vector_type(8)));

#define INF   8192             // in_features
#define FOLDS 127
#define LOCAL 128
#define OUTF  (FOLDS * LOCAL)  // 16256
#define BM    128

// W bf16 scratch: 127*128*128 bf16 = 4,161,536 bytes
#define WB_BYTES ((size_t)FOLDS * LOCAL * 128 * 2)

__global__ void convert_w_kernel(const float* __restrict__ W, __bf16* __restrict__ Wb) {
    const size_t i = ((size_t)blockIdx.x * 256 + threadIdx.x) * 8;
    f32x4 v0 = *(const f32x4*)(W + i);
    f32x4 v1 = *(const f32x4*)(W + i + 4);
    bf16x8 w;
    w[0] = (__bf16)v0[0]; w[1] = (__bf16)v0[1]; w[2] = (__bf16)v0[2]; w[3] = (__bf16)v0[3];
    w[4] = (__bf16)v1[0]; w[5] = (__bf16)v1[1]; w[6] = (__bf16)v1[2]; w[7] = (__bf16)v1[3];
    *(bf16x8*)(Wb + i) = w;
}

__device__ __forceinline__ void cvt_store8(char* lds, int byte, f32x4 v0, f32x4 v1) {
    bf16x8 w;
    w[0] = (__bf16)v0[0]; w[1] = (__bf16)v0[1]; w[2] = (__bf16)v0[2]; w[3] = (__bf16)v0[3];
    w[4] = (__bf16)v1[0]; w[5] = (__bf16)v1[1]; w[6] = (__bf16)v1[2]; w[7] = (__bf16)v1[3];
    *(bf16x8*)(lds + byte) = w;
}

// A window: 128 rows x 192 cols bf16 (row stride 384B), XOR swizzle byte^=(row&7)<<4
// B tile:   128 rows x 128 cols bf16 (row stride 256B), same swizzle
template<bool WBF16>
__global__ __launch_bounds__(256, 2)
void local_linear_kernel(const float* __restrict__ x,
                         const float* __restrict__ Wf32,
                         const __bf16* __restrict__ Wbf,
                         const float* __restrict__ bias,
                         float* __restrict__ out)
{
    __shared__ __align__(16) __bf16 As[128 * 192];   // 48 KiB
    __shared__ __align__(16) __bf16 Bs[128 * 128];   // 32 KiB

    const int mt = blockIdx.x;       // batch tile 0..15
    const int fg = blockIdx.y;       // fold group 0..63
    const int f0 = fg * 2;           // first fold of pair
    const bool has_f1 = (f0 + 1) < FOLDS;
    const int t  = threadIdx.x;

    const int m0 = mt * BM;
    const float* __restrict__ xg = x + (size_t)m0 * INF + (size_t)f0 * 64;

    const int lane = t & 63;
    const int wid  = t >> 6;
    const int wm   = wid >> 1;
    const int wn   = wid & 1;
    const int r16  = lane & 15;
    const int kq   = lane >> 4;

    // ---- stage B for fold f (bf16 gload_lds path or fp32 reg path) ----
    auto stageB = [&](int f) {
        if constexpr (WBF16) {
            const char* Wsrc = (const char*)(Wbf + (size_t)f * LOCAL * 128);
            #pragma unroll
            for (int c = 0; c < 8; ++c) {
                const int base  = wid * 8192 + c * 1024;        // wave-uniform LDS byte base
                const int b     = base + lane * 16;             // this lane's dest byte
                const int row   = b >> 8;
                const int inner = b & 255;
                const int srcb  = row * 256 + (inner ^ ((row & 7) << 4)); // inverse swizzle
                __builtin_amdgcn_global_load_lds(
                    (const __attribute__((address_space(1))) void*)(Wsrc + srcb),
                    (__attribute__((address_space(3))) void*)((char*)Bs + base),
                    16, 0, 0);
            }
        } else {
            const float* Wf = Wf32 + (size_t)f * LOCAL * 128;
            #pragma unroll
            for (int it = 0; it < 8; ++it) {
                const int e = it * 2048 + t * 8;
                const int row = e >> 7, col = e & 127;
                const float* g = Wf + row * 128 + col;
                f32x4 v0 = *(const f32x4*)g;
                f32x4 v1 = *(const f32x4*)(g + 4);
                cvt_store8((char*)Bs, (row * 256 + col * 2) ^ ((row & 7) << 4), v0, v1);
            }
        }
    };

    stageB(f0);

    // ---- stage A window section 1: cols 0..127 ----
    #pragma unroll
    for (int it = 0; it < 8; ++it) {
        const int e = it * 2048 + t * 8;
        const int row = e >> 7, col = e & 127;
        const float* g = xg + (size_t)row * INF + col;
        f32x4 v0 = *(const f32x4*)g;
        f32x4 v1 = *(const f32x4*)(g + 4);
        cvt_store8((char*)As, (row * 384 + col * 2) ^ ((row & 7) << 4), v0, v1);
    }
    // ---- section 2: cols 128..191 (only if second fold exists) ----
    if (has_f1) {
        #pragma unroll
        for (int it = 0; it < 4; ++it) {
            const int e = it * 2048 + t * 8;
            const int row = e >> 6, col = 128 + (e & 63);
            const float* g = xg + (size_t)row * INF + col;
            f32x4 v0 = *(const f32x4*)g;
            f32x4 v1 = *(const f32x4*)(g + 4);
            cvt_store8((char*)As, (row * 384 + col * 2) ^ ((row & 7) << 4), v0, v1);
        }
    }

    // ---- compute + store for one fold ----
    auto computeFold = [&](int f, int acolBase) {
        f32x4 acc[4][4];
        #pragma unroll
        for (int i = 0; i < 4; ++i)
            #pragma unroll
            for (int j = 0; j < 4; ++j)
                acc[i][j] = (f32x4){0.f, 0.f, 0.f, 0.f};

        #pragma unroll
        for (int ks = 0; ks < 4; ++ks) {
            const int kof = ks * 32 + kq * 8;
            bf16x8 a[4], b[4];
            #pragma unroll
            for (int i = 0; i < 4; ++i) {
                const int row  = wm * 64 + i * 16 + r16;
                const int byte = (row * 384 + (acolBase + kof) * 2) ^ ((row & 7) << 4);
                a[i] = *(const bf16x8*)((const char*)As + byte);
            }
            #pragma unroll
            for (int j = 0; j < 4; ++j) {
                const int row  = wn * 64 + j * 16 + r16;
                const int byte = (row * 256 + kof * 2) ^ ((row & 7) << 4);
                b[j] = *(const bf16x8*)((const char*)Bs + byte);
            }
            #pragma unroll
            for (int i = 0; i < 4; ++i)
                #pragma unroll
                for (int j = 0; j < 4; ++j)
                    acc[i][j] = __builtin_amdgcn_mfma_f32_16x16x32_bf16(a[i], b[j], acc[i][j], 0, 0, 0);
        }

        float bv[4];
        #pragma unroll
        for (int j = 0; j < 4; ++j)
            bv[j] = bias[f * LOCAL + wn * 64 + j * 16 + r16];

        #pragma unroll
        for (int i = 0; i < 4; ++i) {
            const int mrow = m0 + wm * 64 + i * 16 + kq * 4;
            #pragma unroll
            for (int j = 0; j < 4; ++j) {
                const int ncol = f * LOCAL + wn * 64 + j * 16 + r16;
                float* o = out + (size_t)mrow * OUTF + ncol;
                #pragma unroll
                for (int r = 0; r < 4; ++r)
                    o[(size_t)r * OUTF] = acc[i][j][r] + bv[j];
            }
        }
    };

    __syncthreads();
    computeFold(f0, 0);

    if (has_f1) {
        __syncthreads();          // all waves done reading Bs(f0)
        stageB(f0 + 1);
        __syncthreads();
        computeFold(f0 + 1, 64);  // fold f0+1 uses A cols 64..191
    }
}

extern "C" void kernel_launch(void* const* d_in, const int* in_sizes, int n_in,
                              void* d_out, int out_size, void* d_ws, size_t ws_size,
                              hipStream_t stream) {
    const float* x    = (const float*)d_in[0];
    const float* W    = (const float*)d_in[1];
    const float* bias = (const float*)d_in[2];
    float* out        = (float*)d_out;

    dim3 grid(2048 / BM, 64);   // 16 x 64 fold-pair groups
    dim3 block(256);

    if (ws_size >= WB_BYTES) {
        __bf16* Wb = (__bf16*)d_ws;
        convert_w_kernel<<<1016, 256, 0, stream>>>(W, Wb);   // 1016*256*8 = 2,080,768 elems
        local_linear_kernel<true><<<grid, block, 0, stream>>>(x, W, Wb, bias, out);
    } else {
        local_linear_kernel<false><<<grid, block, 0, stream>>>(x, W, nullptr, bias, out);
    }
}